// Round 5
// baseline (852.919 us; speedup 1.0000x reference)
//
#include <hip/hip_runtime.h>

#define DD 32
#define NEG_SLOPE 0.01f
#define BN_EPS 1e-5f
#define SB 256          // stats partial blocks

// ======================= helper kernels ====================================

__global__ void zero_kernel(float* p, int n) {
    int i = blockIdx.x * blockDim.x + threadIdx.x;
    if (i < n) p[i] = 0.0f;
}

__global__ void zero_int_kernel(int* p, int n) {
    int i = blockIdx.x * blockDim.x + threadIdx.x;
    if (i < n) p[i] = 0;
}

// ======================= CSR build =========================================

__global__ void hist_kernel(const int* dst, int* deg, int E) {
    int e = blockIdx.x * blockDim.x + threadIdx.x;
    if (e < E) atomicAdd(&deg[dst[e]], 1);
}

__global__ void scan_block_kernel(const int* deg, int* pre, int* bsum, int N) {
    __shared__ int sh[1024];
    int tid = threadIdx.x;
    int i = blockIdx.x * 1024 + tid;
    int v = (i < N) ? deg[i] : 0;
    sh[tid] = v;
    __syncthreads();
    for (int off = 1; off < 1024; off <<= 1) {
        int t = (tid >= off) ? sh[tid - off] : 0;
        __syncthreads();
        sh[tid] += t;
        __syncthreads();
    }
    if (i < N) pre[i] = sh[tid] - v;         // exclusive
    if (tid == 1023) bsum[blockIdx.x] = sh[1023];
}

__global__ void scan_sums_kernel(const int* bsum, int* boff, int nb) {
    if (threadIdx.x == 0) {
        int run = 0;
        for (int i = 0; i < nb; ++i) { boff[i] = run; run += bsum[i]; }
    }
}

// rowptr += block offsets; also seed cursor with the final rowptr
__global__ void add_off_kernel(int* rowptr, int* cursor, const int* boff, int N, int E) {
    int i = blockIdx.x * blockDim.x + threadIdx.x;
    if (i < N) {
        int v = rowptr[i] + boff[i >> 10];
        rowptr[i] = v;
        cursor[i] = v;
    }
    if (i == 0) rowptr[N] = E;
}

// one 8B packed store per edge: perm[p] = {src, bitcast(w)}
__global__ void fill_kernel(const int* src, const int* dst, const float* ew,
                            int* cursor, int2* perm, int E) {
    int e = blockIdx.x * blockDim.x + threadIdx.x;
    if (e >= E) return;
    int p = atomicAdd(&cursor[dst[e]], 1);
    int2 q;
    q.x = src[e];
    q.y = __float_as_int(ew[e]);
    perm[p] = q;
}

// ======================= gather propagation ================================
// out[n][c] = sum_j w_j * f(x[src_j][c]),  f = identity or BN+leaky (fused)
template <bool BN>
__global__ void gather_prop_kernel(const float* x, const int* rowptr,
                                   const int2* perm, float* out, int N,
                                   const float* st, const float* gamma,
                                   const float* beta, float invN) {
    int t = blockIdx.x * blockDim.x + threadIdx.x;
    int n = t >> 5;
    if (n >= N) return;
    int c = t & 31;
    float a = 0.f, bc = 0.f;
    if (BN) {
        float m   = st[c] * invN;
        float msq = st[DD + c] * invN;
        float inv = 1.0f / sqrtf(msq - m * m + BN_EPS);
        a  = inv * gamma[c];
        bc = beta[c] - m * a;
    }
    int b = rowptr[n], e = rowptr[n + 1];
    float acc = 0.f;
    for (int j = b; j < e; ++j) {
        int2 q = perm[j];
        float xv = x[q.x * DD + c];
        if (BN) {
            xv = xv * a + bc;
            xv = xv >= 0.f ? xv : NEG_SLOPE * xv;
        }
        acc += __int_as_float(q.y) * xv;
    }
    out[n * DD + c] = acc;
}

// ======================= combine ===========================================
// out[n][c] = bias[c] + sum_d f(x0[n][d])*W[0][d][c] + x1*W[1] + x2*W[2]
// out may alias x0 (in-place): all of a wave's row loads precede its stores.
template <bool BN>
__global__ void combine_kernel(const float* x0, const float* x1, const float* x2,
                               const float* W, const float* bias,
                               float* out, int N,
                               const float* st, const float* gamma,
                               const float* beta, float invN) {
    int t = blockIdx.x * blockDim.x + threadIdx.x;
    int n = t >> 5;
    if (n >= N) return;
    int c = t & 31;
    const float* r0 = x0 + n * DD;
    const float* r1 = x1 + n * DD;
    const float* r2 = x2 + n * DD;
    float acc = bias[c];
    for (int d = 0; d < DD; ++d) {
        float v0 = r0[d];
        if (BN) {
            float m   = st[d] * invN;
            float msq = st[DD + d] * invN;
            float inv = 1.0f / sqrtf(msq - m * m + BN_EPS);
            float a   = inv * gamma[d];
            float bc  = beta[d] - m * a;
            v0 = v0 * a + bc;
            v0 = v0 >= 0.f ? v0 : NEG_SLOPE * v0;
        }
        acc += v0 * W[d * DD + c];
        acc += r1[d] * W[DD * DD + d * DD + c];
        acc += r2[d] * W[2 * DD * DD + d * DD + c];
    }
    out[t] = acc;
}

// ======================= stats (deterministic, proven) =====================

__global__ void stats_part_kernel(const float* x, float* part, int total) {
    int tid = threadIdx.x;
    int idx = blockIdx.x * 256 + tid;
    const int stride = SB * 256;
    float s = 0.f, ss = 0.f;
    for (int i = idx; i < total; i += stride) { float v = x[i]; s += v; ss += v * v; }
    __shared__ float sh[2][8][DD];
    sh[0][tid >> 5][tid & 31] = s;
    sh[1][tid >> 5][tid & 31] = ss;
    __syncthreads();
    if (tid < DD) {
        float ts = 0.f, tss = 0.f;
        for (int g = 0; g < 8; ++g) { ts += sh[0][g][tid]; tss += sh[1][g][tid]; }
        part[blockIdx.x * 64 + tid] = ts;
        part[blockIdx.x * 64 + DD + tid] = tss;
    }
}

__global__ void stats_final_kernel(const float* part, float* st) {
    int tid = threadIdx.x;                   // 64 threads
    if (tid < 64) {
        float a = 0.f;
        for (int b = 0; b < SB; ++b) a += part[b * 64 + tid];
        st[tid] = a;
    }
}

__global__ void bnrelu_kernel(const float* x, const float* stats,
                              const float* gamma, const float* beta,
                              float* out, int total, float invN) {
    int i = blockIdx.x * blockDim.x + threadIdx.x;
    if (i >= total) return;
    int c = i & 31;
    float m   = stats[c] * invN;
    float msq = stats[DD + c] * invN;
    float var = msq - m * m;
    float inv = 1.0f / sqrtf(var + BN_EPS);
    float v = (x[i] - m) * inv * gamma[c] + beta[c];
    out[i] = v >= 0.f ? v : NEG_SLOPE * v;
}

// ======================= fallback scatter path (round-3, proven) ===========

__global__ void prop_kernel(const float* x, const int* src, const int* dst,
                            const float* ew, float* out, int E) {
    int t = blockIdx.x * blockDim.x + threadIdx.x;
    int e = t >> 5;
    if (e >= E) return;
    int c = t & 31;
    float v = ew[e] * x[src[e] * DD + c];
    atomicAdd(&out[dst[e] * DD + c], v);
}

__global__ void stats_kernel(const float* x, float* stats, int N) {
    int c = blockIdx.x;
    int tid = threadIdx.x;
    float s = 0.f, ss = 0.f;
    for (int r = tid; r < N; r += 1024) {
        float v = x[r * DD + c];
        s += v; ss += v * v;
    }
    __shared__ float shs[1024];
    __shared__ float shq[1024];
    shs[tid] = s; shq[tid] = ss;
    __syncthreads();
    for (int off = 512; off > 0; off >>= 1) {
        if (tid < off) { shs[tid] += shs[tid + off]; shq[tid] += shq[tid + off]; }
        __syncthreads();
    }
    if (tid == 0) { stats[c] = shs[0]; stats[DD + c] = shq[0]; }
}

// ===========================================================================

extern "C" void kernel_launch(void* const* d_in, const int* in_sizes, int n_in,
                              void* d_out, int out_size, void* d_ws, size_t ws_size,
                              hipStream_t stream) {
    const float* y   = (const float*)d_in[0];
    const int*   ei  = (const int*)d_in[1];
    const float* ew  = (const float*)d_in[2];
    const float* W1  = (const float*)d_in[3];
    const float* b1  = (const float*)d_in[4];
    const float* g1  = (const float*)d_in[5];
    const float* be1 = (const float*)d_in[6];
    const float* W2  = (const float*)d_in[7];
    const float* b2  = (const float*)d_in[8];
    const float* g2  = (const float*)d_in[9];
    const float* be2 = (const float*)d_in[10];
    float* out = (float*)d_out;

    const int N = in_sizes[0] / DD;     // 100000
    const int E = in_sizes[2];          // 1600000
    const int total = N * DD;

    const int* src = ei;
    const int* dst = ei + E;

    // persistent ws layout (RP padded even so perm is 8B-aligned)
    const int RP = (N + 2) & ~1;                 // 100002
    float* st     = (float*)d_ws;                // 128 f
    float* h1     = st + 128;                    // total f
    float* h2     = h1 + total;                  // total f
    int*   rowptr = (int*)(h2 + total);          // RP i
    int2*  perm   = (int2*)(rowptr + RP);        // E int2
    float* part   = (float*)(perm + E);          // SB*64 f

    const size_t need = ((size_t)128 + 2 * (size_t)total + RP + 2 * (size_t)E + SB * 64) * 4;
    const bool use_csr = ws_size >= need;

    // scratch temporaries aliased into h1/h2 (dead once gathers start)
    int* cursor = (int*)h1;                      // N i
    int* bsum   = (int*)h1 + N;                  // ≤128 i
    int* boff   = bsum + 128;                    // ≤128 i
    int* deg    = (int*)h2;                      // N i

    const int NB = (N + 1023) / 1024;            // 98
    const float invN = 1.0f / (float)N;
    dim3 blk(256);
    const int ngrid = (N + 255) / 256;
    const int egrid = (E + 255) / 256;
    const int cgrid = (total + 255) / 256;
    const int zgrid = (2 * total + 255) / 256;
    const int pgrid = (E * DD + 255) / 256;

    if (use_csr) {
        // ---- build CSR by destination ----
        zero_int_kernel<<<ngrid, blk, 0, stream>>>(deg, N);
        hist_kernel<<<egrid, blk, 0, stream>>>(dst, deg, E);
        scan_block_kernel<<<NB, 1024, 0, stream>>>(deg, rowptr, bsum, N);
        scan_sums_kernel<<<1, 64, 0, stream>>>(bsum, boff, NB);
        add_off_kernel<<<ngrid, blk, 0, stream>>>(rowptr, cursor, boff, N, E);
        fill_kernel<<<egrid, blk, 0, stream>>>(src, dst, ew, cursor, perm, E);

        // ---- layer 1 ----  (z1 raw in d_out; BN deferred/fused into layer 2)
        gather_prop_kernel<false><<<cgrid, blk, 0, stream>>>(y,  rowptr, perm, h1, N, nullptr, nullptr, nullptr, 0.f);
        gather_prop_kernel<false><<<cgrid, blk, 0, stream>>>(h1, rowptr, perm, h2, N, nullptr, nullptr, nullptr, 0.f);
        combine_kernel<false><<<cgrid, blk, 0, stream>>>(y, h1, h2, W1, b1, out, N, nullptr, nullptr, nullptr, 0.f);
        stats_part_kernel<<<SB, blk, 0, stream>>>(out, part, total);
        stats_final_kernel<<<1, 64, 0, stream>>>(part, st);

        // ---- layer 2 ----  (BN+leaky of layer 1 applied on the fly)
        gather_prop_kernel<true><<<cgrid, blk, 0, stream>>>(out, rowptr, perm, h1, N, st, g1, be1, invN);
        gather_prop_kernel<false><<<cgrid, blk, 0, stream>>>(h1, rowptr, perm, h2, N, nullptr, nullptr, nullptr, 0.f);
        combine_kernel<true><<<cgrid, blk, 0, stream>>>(out, h1, h2, W2, b2, out, N, st, g1, be1, invN);
        stats_part_kernel<<<SB, blk, 0, stream>>>(out, part, total);
        stats_final_kernel<<<1, 64, 0, stream>>>(part, st + 64);
        bnrelu_kernel<<<cgrid, blk, 0, stream>>>(out, st + 64, g2, be2, out, total, invN);
    } else {
        // ---- fallback: exact round-3 path ----
        zero_kernel<<<zgrid, blk, 0, stream>>>(h1, 2 * total);
        prop_kernel<<<pgrid, blk, 0, stream>>>(y,  src, dst, ew, h1, E);
        prop_kernel<<<pgrid, blk, 0, stream>>>(h1, src, dst, ew, h2, E);
        combine_kernel<false><<<cgrid, blk, 0, stream>>>(y, h1, h2, W1, b1, out, N, nullptr, nullptr, nullptr, 0.f);
        stats_kernel<<<32, 1024, 0, stream>>>(out, st, N);
        bnrelu_kernel<<<cgrid, blk, 0, stream>>>(out, st, g1, be1, out, total, invN);

        zero_kernel<<<zgrid, blk, 0, stream>>>(h1, 2 * total);
        prop_kernel<<<pgrid, blk, 0, stream>>>(out, src, dst, ew, h1, E);
        prop_kernel<<<pgrid, blk, 0, stream>>>(h1,  src, dst, ew, h2, E);
        combine_kernel<false><<<cgrid, blk, 0, stream>>>(out, h1, h2, W2, b2, out, N, nullptr, nullptr, nullptr, 0.f);
        stats_kernel<<<32, 1024, 0, stream>>>(out, st + 2 * DD, N);
        bnrelu_kernel<<<cgrid, blk, 0, stream>>>(out, st + 2 * DD, g2, be2, out, total, invN);
    }
}

// Round 6
// 678.415 us; speedup vs baseline: 1.2572x; 1.2572x over previous
//
#include <hip/hip_runtime.h>

#define DD 32
#define NEG_SLOPE 0.01f
#define BN_EPS 1e-5f
#define SB 256          // stats partial blocks

// ======================= helper kernels ====================================

__global__ void zero_kernel(float* p, int n) {
    int i = blockIdx.x * blockDim.x + threadIdx.x;
    if (i < n) p[i] = 0.0f;
}

__global__ void zero_int_kernel(int* p, int n) {
    int i = blockIdx.x * blockDim.x + threadIdx.x;
    if (i < n) p[i] = 0;
}

// ======================= CSR build =========================================

__global__ void hist_kernel(const int* dst, int* deg, int E) {
    int e = blockIdx.x * blockDim.x + threadIdx.x;
    if (e < E) atomicAdd(&deg[dst[e]], 1);
}

__global__ void scan_block_kernel(const int* deg, int* pre, int* bsum, int N) {
    __shared__ int sh[1024];
    int tid = threadIdx.x;
    int i = blockIdx.x * 1024 + tid;
    int v = (i < N) ? deg[i] : 0;
    sh[tid] = v;
    __syncthreads();
    for (int off = 1; off < 1024; off <<= 1) {
        int t = (tid >= off) ? sh[tid - off] : 0;
        __syncthreads();
        sh[tid] += t;
        __syncthreads();
    }
    if (i < N) pre[i] = sh[tid] - v;         // exclusive
    if (tid == 1023) bsum[blockIdx.x] = sh[1023];
}

__global__ void scan_sums_kernel(const int* bsum, int* boff, int nb) {
    if (threadIdx.x == 0) {
        int run = 0;
        for (int i = 0; i < nb; ++i) { boff[i] = run; run += bsum[i]; }
    }
}

__global__ void add_off_kernel(int* rowptr, int* cursor, const int* boff, int N, int E) {
    int i = blockIdx.x * blockDim.x + threadIdx.x;
    if (i < N) {
        int v = rowptr[i] + boff[i >> 10];
        rowptr[i] = v;
        cursor[i] = v;
    }
    if (i == 0) rowptr[N] = E;
}

// one 8B packed store per edge: perm[p] = {src, bitcast(w)}
__global__ void fill_kernel(const int* src, const int* dst, const float* ew,
                            int* cursor, int2* perm, int E) {
    int e = blockIdx.x * blockDim.x + threadIdx.x;
    if (e >= E) return;
    int p = atomicAdd(&cursor[dst[e]], 1);
    int2 q;
    q.x = src[e];
    q.y = __float_as_int(ew[e]);
    perm[p] = q;
}

// ======================= gather propagation ================================
// out[n][c] = sum_j w_j * x[src_j][c]; 2 edges/iter via aligned int4 loads.
__global__ void gather_prop_kernel(const float* __restrict__ x,
                                   const int* __restrict__ rowptr,
                                   const int2* __restrict__ perm,
                                   float* __restrict__ out, int N) {
    int t = blockIdx.x * blockDim.x + threadIdx.x;
    int n = t >> 5;
    if (n >= N) return;
    int c = t & 31;
    int b = rowptr[n], e = rowptr[n + 1];
    float acc = 0.f;
    int j = b;
    if ((j & 1) && j < e) {                       // peel to 16B alignment
        int2 q = perm[j];
        acc += __int_as_float(q.y) * x[q.x * DD + c];
        ++j;
    }
    for (; j + 1 < e; j += 2) {
        int4 q = *reinterpret_cast<const int4*>(perm + j);
        acc += __int_as_float(q.y) * x[q.x * DD + c];
        acc += __int_as_float(q.w) * x[q.z * DD + c];
    }
    if (j < e) {
        int2 q = perm[j];
        acc += __int_as_float(q.y) * x[q.x * DD + c];
    }
    out[n * DD + c] = acc;
}

// ======================= combine v3 ========================================
// out[n][c] = sum_d x0[n][d]*W0[d][c] + x1[n][d]*W1[d][c] + x2[n][d]*W2[d][c]
// (bias dropped: BN's mean-subtraction cancels any per-column constant exactly)
// Lane c keeps its three W-columns in 96 registers (persistent grid amortizes
// the preload); x-rows come in as broadcast float4s. In-place on x0 is safe:
// a wave's row loads all precede its row store; rows are group-private.
__global__ __launch_bounds__(256, 3)
void combine_v3(const float* x0, const float* __restrict__ x1,
                const float* __restrict__ x2, const float* __restrict__ W,
                float* out, int N) {
    int c = threadIdx.x & 31;
    float w0[DD], w1[DD], w2[DD];
#pragma unroll
    for (int d = 0; d < DD; ++d) {
        w0[d] = W[d * DD + c];
        w1[d] = W[DD * DD + d * DD + c];
        w2[d] = W[2 * DD * DD + d * DD + c];
    }
    int group   = (blockIdx.x * blockDim.x + threadIdx.x) >> 5;
    int ngroups = (gridDim.x * blockDim.x) >> 5;
    for (int n = group; n < N; n += ngroups) {
        const float4* r0 = reinterpret_cast<const float4*>(x0 + (size_t)n * DD);
        const float4* r1 = reinterpret_cast<const float4*>(x1 + (size_t)n * DD);
        const float4* r2 = reinterpret_cast<const float4*>(x2 + (size_t)n * DD);
        float acc = 0.f;
#pragma unroll
        for (int q = 0; q < DD / 4; ++q) {
            float4 v0 = r0[q];
            float4 v1 = r1[q];
            float4 v2 = r2[q];
            acc += v0.x * w0[4*q]   + v0.y * w0[4*q+1] + v0.z * w0[4*q+2] + v0.w * w0[4*q+3];
            acc += v1.x * w1[4*q]   + v1.y * w1[4*q+1] + v1.z * w1[4*q+2] + v1.w * w1[4*q+3];
            acc += v2.x * w2[4*q]   + v2.y * w2[4*q+1] + v2.z * w2[4*q+2] + v2.w * w2[4*q+3];
        }
        out[(size_t)n * DD + c] = acc;
    }
}

// ======================= stats (deterministic, proven) =====================

__global__ void stats_part_kernel(const float* x, float* part, int total) {
    int tid = threadIdx.x;
    int idx = blockIdx.x * 256 + tid;
    const int stride = SB * 256;
    float s = 0.f, ss = 0.f;
    for (int i = idx; i < total; i += stride) { float v = x[i]; s += v; ss += v * v; }
    __shared__ float sh[2][8][DD];
    sh[0][tid >> 5][tid & 31] = s;
    sh[1][tid >> 5][tid & 31] = ss;
    __syncthreads();
    if (tid < DD) {
        float ts = 0.f, tss = 0.f;
        for (int g = 0; g < 8; ++g) { ts += sh[0][g][tid]; tss += sh[1][g][tid]; }
        part[blockIdx.x * 64 + tid] = ts;
        part[blockIdx.x * 64 + DD + tid] = tss;
    }
}

__global__ void stats_final_kernel(const float* part, float* st) {
    int tid = threadIdx.x;                   // 64 threads
    if (tid < 64) {
        float a = 0.f;
        for (int b = 0; b < SB; ++b) a += part[b * 64 + tid];
        st[tid] = a;
    }
}

__global__ void bnrelu_kernel(const float* x, const float* stats,
                              const float* gamma, const float* beta,
                              float* out, int total, float invN) {
    int i = blockIdx.x * blockDim.x + threadIdx.x;
    if (i >= total) return;
    int c = i & 31;
    float m   = stats[c] * invN;
    float msq = stats[DD + c] * invN;
    float var = msq - m * m;
    float inv = 1.0f / sqrtf(var + BN_EPS);
    float v = (x[i] - m) * inv * gamma[c] + beta[c];
    out[i] = v >= 0.f ? v : NEG_SLOPE * v;
}

// ======================= fallback path (round-3, proven) ===================

__global__ void prop_kernel(const float* x, const int* src, const int* dst,
                            const float* ew, float* out, int E) {
    int t = blockIdx.x * blockDim.x + threadIdx.x;
    int e = t >> 5;
    if (e >= E) return;
    int c = t & 31;
    float v = ew[e] * x[src[e] * DD + c];
    atomicAdd(&out[dst[e] * DD + c], v);
}

__global__ void combine_basic(const float* x0, const float* x1, const float* x2,
                              const float* W, const float* bias,
                              float* out, int N) {
    int t = blockIdx.x * blockDim.x + threadIdx.x;
    int n = t >> 5;
    if (n >= N) return;
    int c = t & 31;
    const float* r0 = x0 + n * DD;
    const float* r1 = x1 + n * DD;
    const float* r2 = x2 + n * DD;
    float acc = bias[c];
    for (int d = 0; d < DD; ++d) {
        acc += r0[d] * W[d * DD + c];
        acc += r1[d] * W[DD * DD + d * DD + c];
        acc += r2[d] * W[2 * DD * DD + d * DD + c];
    }
    out[t] = acc;
}

__global__ void stats_kernel(const float* x, float* stats, int N) {
    int c = blockIdx.x;
    int tid = threadIdx.x;
    float s = 0.f, ss = 0.f;
    for (int r = tid; r < N; r += 1024) {
        float v = x[r * DD + c];
        s += v; ss += v * v;
    }
    __shared__ float shs[1024];
    __shared__ float shq[1024];
    shs[tid] = s; shq[tid] = ss;
    __syncthreads();
    for (int off = 512; off > 0; off >>= 1) {
        if (tid < off) { shs[tid] += shs[tid + off]; shq[tid] += shq[tid + off]; }
        __syncthreads();
    }
    if (tid == 0) { stats[c] = shs[0]; stats[DD + c] = shq[0]; }
}

// ===========================================================================

extern "C" void kernel_launch(void* const* d_in, const int* in_sizes, int n_in,
                              void* d_out, int out_size, void* d_ws, size_t ws_size,
                              hipStream_t stream) {
    const float* y   = (const float*)d_in[0];
    const int*   ei  = (const int*)d_in[1];
    const float* ew  = (const float*)d_in[2];
    const float* W1  = (const float*)d_in[3];
    const float* b1  = (const float*)d_in[4];
    const float* g1  = (const float*)d_in[5];
    const float* be1 = (const float*)d_in[6];
    const float* W2  = (const float*)d_in[7];
    const float* b2  = (const float*)d_in[8];
    const float* g2  = (const float*)d_in[9];
    const float* be2 = (const float*)d_in[10];
    float* out = (float*)d_out;

    const int N = in_sizes[0] / DD;     // 100000
    const int E = in_sizes[2];          // 1600000
    const int total = N * DD;

    const int* src = ei;
    const int* dst = ei + E;

    // persistent ws layout; RP multiple of 4 so perm (int2) is 16B-aligned
    const int RP = (N + 4) & ~3;                 // 100004
    float* st     = (float*)d_ws;                // 128 f
    float* h1     = st + 128;                    // total f
    float* h2     = h1 + total;                  // total f
    int*   rowptr = (int*)(h2 + total);          // RP i (rowptr[N]=E used)
    int2*  perm   = (int2*)(rowptr + RP);        // E int2, 16B-aligned
    float* part   = (float*)(perm + E);          // SB*64 f

    const size_t need = ((size_t)128 + 2 * (size_t)total + RP + 2 * (size_t)E + SB * 64) * 4;
    const bool use_csr = ws_size >= need;

    // scratch temporaries aliased into h1/h2 (dead once gathers start)
    int* cursor = (int*)h1;                      // N i
    int* bsum   = (int*)h1 + N;                  // ≤128 i
    int* boff   = bsum + 128;                    // ≤128 i
    int* deg    = (int*)h2;                      // N i

    const int NB = (N + 1023) / 1024;            // 98
    const float invN = 1.0f / (float)N;
    dim3 blk(256);
    const int ngrid = (N + 255) / 256;
    const int egrid = (E + 255) / 256;
    const int cgrid = (total + 255) / 256;
    const int zgrid = (2 * total + 255) / 256;
    const int pgrid = (E * DD + 255) / 256;
    const int vgrid = 1024;                      // persistent combine_v3 grid

    if (use_csr) {
        // ---- build CSR by destination ----
        zero_int_kernel<<<ngrid, blk, 0, stream>>>(deg, N);
        hist_kernel<<<egrid, blk, 0, stream>>>(dst, deg, E);
        scan_block_kernel<<<NB, 1024, 0, stream>>>(deg, rowptr, bsum, N);
        scan_sums_kernel<<<1, 64, 0, stream>>>(bsum, boff, NB);
        add_off_kernel<<<ngrid, blk, 0, stream>>>(rowptr, cursor, boff, N, E);
        fill_kernel<<<egrid, blk, 0, stream>>>(src, dst, ew, cursor, perm, E);

        // ---- layer 1 ----
        gather_prop_kernel<<<cgrid, blk, 0, stream>>>(y,  rowptr, perm, h1, N);
        gather_prop_kernel<<<cgrid, blk, 0, stream>>>(h1, rowptr, perm, h2, N);
        combine_v3<<<vgrid, blk, 0, stream>>>(y, h1, h2, W1, out, N);
        stats_part_kernel<<<SB, blk, 0, stream>>>(out, part, total);
        stats_final_kernel<<<1, 64, 0, stream>>>(part, st);
        bnrelu_kernel<<<cgrid, blk, 0, stream>>>(out, st, g1, be1, out, total, invN);

        // ---- layer 2 ----
        gather_prop_kernel<<<cgrid, blk, 0, stream>>>(out, rowptr, perm, h1, N);
        gather_prop_kernel<<<cgrid, blk, 0, stream>>>(h1, rowptr, perm, h2, N);
        combine_v3<<<vgrid, blk, 0, stream>>>(out, h1, h2, W2, out, N);
        stats_part_kernel<<<SB, blk, 0, stream>>>(out, part, total);
        stats_final_kernel<<<1, 64, 0, stream>>>(part, st + 64);
        bnrelu_kernel<<<cgrid, blk, 0, stream>>>(out, st + 64, g2, be2, out, total, invN);
    } else {
        // ---- fallback: round-3 proven path ----
        zero_kernel<<<zgrid, blk, 0, stream>>>(h1, 2 * total);
        prop_kernel<<<pgrid, blk, 0, stream>>>(y,  src, dst, ew, h1, E);
        prop_kernel<<<pgrid, blk, 0, stream>>>(h1, src, dst, ew, h2, E);
        combine_basic<<<cgrid, blk, 0, stream>>>(y, h1, h2, W1, b1, out, N);
        stats_kernel<<<32, 1024, 0, stream>>>(out, st, N);
        bnrelu_kernel<<<cgrid, blk, 0, stream>>>(out, st, g1, be1, out, total, invN);

        zero_kernel<<<zgrid, blk, 0, stream>>>(h1, 2 * total);
        prop_kernel<<<pgrid, blk, 0, stream>>>(out, src, dst, ew, h1, E);
        prop_kernel<<<pgrid, blk, 0, stream>>>(h1,  src, dst, ew, h2, E);
        combine_basic<<<cgrid, blk, 0, stream>>>(out, h1, h2, W2, b2, out, N);
        stats_kernel<<<32, 1024, 0, stream>>>(out, st + 2 * DD, N);
        bnrelu_kernel<<<cgrid, blk, 0, stream>>>(out, st + 2 * DD, g2, be2, out, total, invN);
    }
}